// Round 1
// baseline (179.136 us; speedup 1.0000x reference)
//
#include <hip/hip_runtime.h>
#include <hip/hip_bf16.h>
#include <math.h>

// Problem constants (from reference)
#define D 64
#define K 512
#define NROWS 65536
#define DECAY 0.99f
#define ONE_MINUS_DECAY (1.0f - 0.99f)
#define COMMIT 0.25f

// ws layout (float offsets)
#define WS_DWT    0              // [K][D] = 32768  dw accumulator (transposed)
#define WS_COUNTS 32768          // [K]   = 512     cluster counts
#define WS_LOSS   33280          // [1]             loss sum
#define WS_ESQ    33344          // [K]   = 512     ||e_k||^2
#define WS_ET     33856          // [K][D]= 32768   embeddings transposed
#define WS_ZERO_FLOATS 33344     // memset region: dw_t + counts + loss (+pad)

// out layout (float offsets)
#define OUT_Q     0              // quantized_st [N][D]
#define OUT_LOSS  4194304
#define OUT_PERP  4194305
#define OUT_IDX   4194306        // [N] indices as float
#define OUT_NEMB  4259842        // new_embeddings [D][K]
#define OUT_HCS   4292610        // hid_cs [K]
#define OUT_HDW   4293122        // hid_dw [D][K]

// ---------------- prep: transpose embeddings + column squared norms ----------
__global__ void vq_prep(const float* __restrict__ emb,  // [D][K]
                        float* __restrict__ e_t,        // [K][D]
                        float* __restrict__ e_sq)       // [K]
{
    int i = blockIdx.x * 256 + threadIdx.x;   // 0..32767
    if (i < K * D) {
        int k = i >> 6, d = i & 63;
        e_t[i] = emb[d * K + k];
    }
    if (i < K) {
        float s = 0.f;
        for (int d = 0; d < D; ++d) { float v = emb[d * K + i]; s += v * v; }
        e_sq[i] = s;
    }
}

// ---------------- main: distances + argmin + gather + scatter ----------------
// block: 256 threads; each block handles BM=64 rows; K scanned in 4 chunks of 128.
#define BM 64
#define BK 128
#define NCHUNK (K / BK)

__global__ __launch_bounds__(256, 2)
void vq_main(const float* __restrict__ x,     // [N][D]
             const float* __restrict__ emb,   // [D][K]
             const float* __restrict__ e_sq,  // [K]
             const float* __restrict__ e_t,   // [K][D]
             float* __restrict__ out_q,       // [N][D]
             float* __restrict__ out_idx,     // [N] (float)
             float* __restrict__ dw_t,        // [K][D] atomic accum
             float* __restrict__ counts,      // [K]  atomic accum
             float* __restrict__ loss_sum)    // [1]  atomic accum
{
    __shared__ float xs[BM * D];       // 16 KB
    __shared__ float es[D * BK];       // 32 KB
    __shared__ float esq_s[BK];
    __shared__ int   idx_s[BM];
    __shared__ float red_s[4];

    const int tid  = threadIdx.x;
    const int row0 = blockIdx.x * BM;

    // stage x tile (coalesced float4)
    {
        const float4* src = (const float4*)(x + (size_t)row0 * D);
        float4* dst = (float4*)xs;
        for (int i = tid; i < BM * D / 4; i += 256) dst[i] = src[i];
    }

    const int tx = tid & 31;   // column group 0..31 (4 cols each)
    const int ty = tid >> 5;   // row group 0..7 (8 rows each)

    float best[8];
    int   bestk[8];
#pragma unroll
    for (int r = 0; r < 8; ++r) { best[r] = 3.0e38f; bestk[r] = 0; }

    for (int c = 0; c < NCHUNK; ++c) {
        __syncthreads();  // protect es from previous chunk's readers
        for (int i = tid * 4; i < D * BK; i += 1024) {
            int d = i >> 7, j = i & 127;
            *(float4*)&es[d * BK + j] = *(const float4*)&emb[d * K + c * BK + j];
        }
        if (tid < BK / 4)
            *(float4*)&esq_s[tid * 4] = *(const float4*)&e_sq[c * BK + tid * 4];
        __syncthreads();

        float acc[8][4];
#pragma unroll
        for (int r = 0; r < 8; ++r)
#pragma unroll
            for (int j = 0; j < 4; ++j) acc[r][j] = 0.f;

        for (int d = 0; d < D; ++d) {
            float4 e4 = *(const float4*)&es[d * BK + tx * 4];
#pragma unroll
            for (int r = 0; r < 8; ++r) {
                float xv = xs[(ty * 8 + r) * D + d];
                acc[r][0] = fmaf(xv, e4.x, acc[r][0]);
                acc[r][1] = fmaf(xv, e4.y, acc[r][1]);
                acc[r][2] = fmaf(xv, e4.z, acc[r][2]);
                acc[r][3] = fmaf(xv, e4.w, acc[r][3]);
            }
        }
        // fold into running argmin (score = ||e||^2 - 2 x.e ; ||x||^2 is row-constant)
#pragma unroll
        for (int r = 0; r < 8; ++r) {
#pragma unroll
            for (int j = 0; j < 4; ++j) {
                float s = esq_s[tx * 4 + j] - 2.0f * acc[r][j];
                int   kk = c * BK + tx * 4 + j;
                if (s < best[r]) { best[r] = s; bestk[r] = kk; }  // k ascends -> first-min kept
            }
        }
    }

    // reduce argmin across the 32 lanes of each half-wave (same ty)
#pragma unroll
    for (int r = 0; r < 8; ++r) {
        float b = best[r]; int bk = bestk[r];
        for (int m = 16; m >= 1; m >>= 1) {
            float ob  = __shfl_xor(b, m, 64);
            int   obk = __shfl_xor(bk, m, 64);
            if (ob < b || (ob == b && obk < bk)) { b = ob; bk = obk; }
        }
        if (tx == 0) idx_s[ty * 8 + r] = bk;
    }
    __syncthreads();

    // quantized gather + loss partial
    float lsum = 0.f;
    for (int i = tid * 4; i < BM * D; i += 1024) {
        int r = i >> 6, d = i & 63;
        int kk = idx_s[r];
        float4 q  = *(const float4*)&e_t[kk * D + d];
        float4 xv = *(const float4*)&xs[r * D + d];
        float dx = q.x - xv.x, dy = q.y - xv.y, dz = q.z - xv.z, dwv = q.w - xv.w;
        lsum += dx * dx + dy * dy + dz * dz + dwv * dwv;
        *(float4*)&out_q[(size_t)(row0 + r) * D + d] = q;
    }
    for (int m = 32; m >= 1; m >>= 1) lsum += __shfl_xor(lsum, m, 64);
    if ((tid & 63) == 0) red_s[tid >> 6] = lsum;
    __syncthreads();
    if (tid == 0)
        atomicAdd(loss_sum, red_s[0] + red_s[1] + red_s[2] + red_s[3]);

    // indices + counts
    if (tid < BM) {
        int kk = idx_s[tid];
        out_idx[row0 + tid] = (float)kk;
        atomicAdd(&counts[kk], 1.0f);
    }

    // dw scatter: dw_t[idx[r]][d] += x[r][d]
    for (int i = tid; i < BM * D; i += 256) {
        int r = i >> 6, d = i & 63;
        atomicAdd(&dw_t[idx_s[r] * D + d], xs[r * D + d]);
    }
}

// ---------------- finalize: EMA, debias, perplexity, new embeddings ----------
__global__ void vq_final(const float* __restrict__ counts,
                         const float* __restrict__ dw_t,     // [K][D]
                         const float* __restrict__ loss_sum,
                         const float* __restrict__ ema_csh,  // [K]
                         const float* __restrict__ ema_dwh,  // [D][K]
                         const int*   __restrict__ counter,
                         float* __restrict__ out_loss,
                         float* __restrict__ out_perp,
                         float* __restrict__ out_nemb,       // [D][K]
                         float* __restrict__ out_hcs,        // [K]
                         float* __restrict__ out_hdw)        // [D][K]
{
    __shared__ float s_stable[K];
    __shared__ float s_red[K];

    const int k = threadIdx.x;  // 512 threads
    const float c = counts[k];
    const float hid = ema_csh[k] * DECAY + c * ONE_MINUS_DECAY;
    out_hcs[k] = hid;

    const int   cnt    = counter[0] + 1;
    const float debias = 1.0f - powf(DECAY, (float)cnt);
    const float upd    = hid / debias;

    // n = sum(updated_cluster_size)
    s_red[k] = upd;
    __syncthreads();
    for (int off = 256; off >= 1; off >>= 1) {
        if (k < off) s_red[k] += s_red[k + off];
        __syncthreads();
    }
    const float n = s_red[0];
    __syncthreads();

    // entropy term for perplexity
    const float p = c * (1.0f / (float)NROWS);
    s_red[k] = p * logf(p + 1e-10f);
    __syncthreads();
    for (int off = 256; off >= 1; off >>= 1) {
        if (k < off) s_red[k] += s_red[k + off];
        __syncthreads();
    }
    const float ent = s_red[0];

    s_stable[k] = (upd + 1e-5f) / (n + (float)K * 1e-5f) * n;
    __syncthreads();

    for (int i = k; i < D * K; i += K) {
        int d = i >> 9, kk = i & (K - 1);
        float hdw = ema_dwh[i] * DECAY + dw_t[kk * D + d] * ONE_MINUS_DECAY;
        out_hdw[i]  = hdw;
        out_nemb[i] = (hdw / debias) / s_stable[kk];
    }

    if (k == 0) {
        out_loss[0] = COMMIT * loss_sum[0] / (float)((size_t)NROWS * D);
        out_perp[0] = expf(-ent);
    }
}

// ---------------- launch ------------------------------------------------------
extern "C" void kernel_launch(void* const* d_in, const int* in_sizes, int n_in,
                              void* d_out, int out_size, void* d_ws, size_t ws_size,
                              hipStream_t stream)
{
    const float* x_in    = (const float*)d_in[0];   // [64,32,32,64]
    const float* emb     = (const float*)d_in[1];   // [64,512]
    const float* ema_csh = (const float*)d_in[2];   // [512]
    const float* ema_dwh = (const float*)d_in[3];   // [64,512]
    const int*   counter = (const int*)d_in[4];     // [1]

    float* ws  = (float*)d_ws;
    float* out = (float*)d_out;

    // zero the atomic accumulators (dw_t, counts, loss)
    hipMemsetAsync(ws, 0, (size_t)WS_ZERO_FLOATS * sizeof(float), stream);

    vq_prep<<<(K * D + 255) / 256, 256, 0, stream>>>(emb, ws + WS_ET, ws + WS_ESQ);

    vq_main<<<NROWS / BM, 256, 0, stream>>>(
        x_in, emb, ws + WS_ESQ, ws + WS_ET,
        out + OUT_Q, out + OUT_IDX,
        ws + WS_DWT, ws + WS_COUNTS, ws + WS_LOSS);

    vq_final<<<1, K, 0, stream>>>(
        ws + WS_COUNTS, ws + WS_DWT, ws + WS_LOSS,
        ema_csh, ema_dwh, counter,
        out + OUT_LOSS, out + OUT_PERP,
        out + OUT_NEMB, out + OUT_HCS, out + OUT_HDW);
}

// Round 3
// 164.523 us; speedup vs baseline: 1.0888x; 1.0888x over previous
//
#include <hip/hip_runtime.h>
#include <hip/hip_bf16.h>
#include <math.h>

// Problem constants (from reference)
#define D 64
#define K 512
#define NROWS 65536
#define DECAY 0.99f
#define ONE_MINUS_DECAY (1.0f - 0.99f)
#define COMMIT 0.25f

// ws layout (float offsets)
#define WS_DWT    0              // [K][D] = 32768  dw accumulator (transposed)
#define WS_COUNTS 32768          // [K]   = 512     cluster counts
#define WS_LOSS   33280          // [1]             loss sum (pad to 33344)
#define WS_ESQ    33344          // [K]   = 512     ||e_k||^2
#define WS_ET     33856          // [K][D]= 32768   embeddings transposed
#define WS_STABLE 66624          // [K]   = 512     stable_cs
#define WS_DEBIAS 67136          // [1]             debias factor
#define WS_ZERO_FLOATS 33344     // zero region: dw_t + counts + loss (+pad)

// out layout (float offsets)
#define OUT_Q     0              // quantized_st [N][D]
#define OUT_LOSS  4194304
#define OUT_PERP  4194305
#define OUT_IDX   4194306        // [N] indices as float
#define OUT_NEMB  4259842        // new_embeddings [D][K]
#define OUT_HCS   4292610        // hid_cs [K]
#define OUT_HDW   4293122        // hid_dw [D][K]

// main-kernel tiling
#define BM 128                   // rows per block
#define BN 128                   // codebook columns per chunk
#define NCHUNK (K / BN)
#define ES_STRIDE 140            // swizzled row stride for es

// xs layout: row stride 68 + monotone quad shift (row>>3)*4.
// Per-row increment = 68 + {0,4} >= 68 > 64 -> NO overlap (round-2 bug fixed).
// Within a wave, the 4 concurrent row-broadcast reads sit on distinct bank
// quads: offset mod 32 = 4r + 16*wave + 4*g.
__device__ __forceinline__ int xs_base(int row) {
    return row * 68 + ((row >> 3) << 2);
}
// es swizzle: 16B chunk c (c = floatcol>>2) of row d lives at float offset
// d*140 + 4c + 4*(c>>3). The 16 chunks read simultaneously (even or odd c)
// land 2-per-bank-quad over 8 quads -> 2-way aliasing (free).
__device__ __forceinline__ int es_off(int d, int c) {
    return d * ES_STRIDE + (c << 2) + ((c >> 3) << 2);
}

// ---------------- prep: zero accumulators + transpose emb + col norms -------
__global__ void vq_prep(const float* __restrict__ emb,  // [D][K]
                        float* __restrict__ ws)
{
    int i = blockIdx.x * 256 + threadIdx.x;   // 0..32767 (128 blocks)
    if (i < WS_ZERO_FLOATS / 4) {             // zero dw_t + counts + loss
        ((float4*)ws)[i] = make_float4(0.f, 0.f, 0.f, 0.f);
    }
    if (i < K * D) {                          // e_t[k][d] = emb[d][k]
        int k = i >> 6, d = i & 63;
        ws[WS_ET + i] = emb[d * K + k];
    }
    if (i < K) {                              // ||e_k||^2
        float s = 0.f;
        for (int d = 0; d < D; ++d) { float v = emb[d * K + i]; s += v * v; }
        ws[WS_ESQ + i] = s;
    }
}

// ---------------- main: distances + argmin + gather + scatter ----------------
__global__ __launch_bounds__(256, 2)
void vq_main(const float* __restrict__ x,     // [N][D]
             const float* __restrict__ emb,   // [D][K]
             const float* __restrict__ e_sq,  // [K]
             const float* __restrict__ e_t,   // [K][D]
             float* __restrict__ out_q,       // [N][D]
             float* __restrict__ out_idx,     // [N] (float)
             float* __restrict__ dw_t,        // [K][D] atomic accum
             float* __restrict__ counts,      // [K]  atomic accum
             float* __restrict__ loss_sum)    // [1]  atomic accum
{
    __shared__ float xs[BM * 68 + 16 * 4 + 16];   // 8784 floats, max used 8759
    __shared__ float es[D * ES_STRIDE];           // 8960 floats (35 KB)
    __shared__ float esq_s[BN];
    __shared__ int   idx_s[BM];
    __shared__ float red_s[4];

    const int tid  = threadIdx.x;
    const int row0 = blockIdx.x * BM;

    // stage x tile (coalesced float4, swizzled rows)
    for (int i = tid; i < BM * (D / 4); i += 256) {
        int row = i >> 4, seg = i & 15;
        float4 v = *(const float4*)(x + (size_t)(row0 + row) * D + seg * 4);
        *(float4*)&xs[xs_base(row) + seg * 4] = v;
    }

    const int tx = tid & 15;   // col group: 8 consecutive cols
    const int ty = tid >> 4;   // row group: 8 consecutive rows
    const int ea_o = (tx << 3) + ((tx >> 2) << 2);   // es_off(0, 2*tx)

    float best[8];
    int   bestk[8];
#pragma unroll
    for (int r = 0; r < 8; ++r) { best[r] = 3.0e38f; bestk[r] = 0; }

    for (int c = 0; c < NCHUNK; ++c) {
        __syncthreads();  // xs staged / es consumers of previous chunk done
        for (int i = tid * 4; i < D * BN; i += 1024) {
            int d = i >> 7, j = i & 127;
            float4 v = *(const float4*)&emb[d * K + c * BN + j];
            *(float4*)&es[es_off(d, j >> 2)] = v;
        }
        if (tid < BN / 4)
            *(float4*)&esq_s[tid * 4] = *(const float4*)&e_sq[c * BN + tid * 4];
        __syncthreads();

        float acc[8][8];
#pragma unroll
        for (int r = 0; r < 8; ++r)
#pragma unroll
            for (int j = 0; j < 8; ++j) acc[r][j] = 0.f;

        for (int d0 = 0; d0 < D; d0 += 4) {
            float4 ea[4], eb[4];
#pragma unroll
            for (int dd = 0; dd < 4; ++dd) {
                const float* rp = &es[(d0 + dd) * ES_STRIDE + ea_o];
                ea[dd] = *(const float4*)rp;
                eb[dd] = *(const float4*)(rp + 4);
            }
#pragma unroll
            for (int r = 0; r < 8; ++r) {
                float4 x4 = *(const float4*)&xs[xs_base(ty * 8 + r) + d0];
                float xv[4] = {x4.x, x4.y, x4.z, x4.w};
#pragma unroll
                for (int dd = 0; dd < 4; ++dd) {
                    acc[r][0] = fmaf(xv[dd], ea[dd].x, acc[r][0]);
                    acc[r][1] = fmaf(xv[dd], ea[dd].y, acc[r][1]);
                    acc[r][2] = fmaf(xv[dd], ea[dd].z, acc[r][2]);
                    acc[r][3] = fmaf(xv[dd], ea[dd].w, acc[r][3]);
                    acc[r][4] = fmaf(xv[dd], eb[dd].x, acc[r][4]);
                    acc[r][5] = fmaf(xv[dd], eb[dd].y, acc[r][5]);
                    acc[r][6] = fmaf(xv[dd], eb[dd].z, acc[r][6]);
                    acc[r][7] = fmaf(xv[dd], eb[dd].w, acc[r][7]);
                }
            }
        }
        // fold into running argmin (score = ||e||^2 - 2 x.e)
#pragma unroll
        for (int r = 0; r < 8; ++r) {
#pragma unroll
            for (int j = 0; j < 8; ++j) {
                float s = esq_s[tx * 8 + j] - 2.0f * acc[r][j];
                int   kk = c * BN + tx * 8 + j;
                if (s < best[r]) { best[r] = s; bestk[r] = kk; }  // k ascends
            }
        }
    }

    // reduce argmin across the 16 lanes of each row group
#pragma unroll
    for (int r = 0; r < 8; ++r) {
        float b = best[r]; int bk = bestk[r];
        for (int m = 8; m >= 1; m >>= 1) {
            float ob  = __shfl_xor(b, m, 64);
            int   obk = __shfl_xor(bk, m, 64);
            if (ob < b || (ob == b && obk < bk)) { b = ob; bk = obk; }
        }
        if (tx == 0) idx_s[ty * 8 + r] = bk;
    }
    __syncthreads();

    // quantized gather + loss partial
    float lsum = 0.f;
    for (int i = tid * 4; i < BM * D; i += 1024) {
        int r = i >> 6, d = i & 63;
        int kk = idx_s[r];
        float4 q  = *(const float4*)&e_t[kk * D + d];
        float4 xv = *(const float4*)&xs[xs_base(r) + d];
        float dx = q.x - xv.x, dy = q.y - xv.y, dz = q.z - xv.z, dwv = q.w - xv.w;
        lsum += dx * dx + dy * dy + dz * dz + dwv * dwv;
        *(float4*)&out_q[(size_t)(row0 + r) * D + d] = q;
    }
    for (int m = 32; m >= 1; m >>= 1) lsum += __shfl_xor(lsum, m, 64);
    if ((tid & 63) == 0) red_s[tid >> 6] = lsum;
    __syncthreads();
    if (tid == 0)
        atomicAdd(loss_sum, red_s[0] + red_s[1] + red_s[2] + red_s[3]);

    // indices + counts
    if (tid < BM) {
        int kk = idx_s[tid];
        out_idx[row0 + tid] = (float)kk;
        atomicAdd(&counts[kk], 1.0f);
    }

    // dw scatter: dw_t[idx[r]][d] += x[r][d]
    for (int i = tid; i < BM * D; i += 256) {
        int r = i >> 6, d = i & 63;
        atomicAdd(&dw_t[idx_s[r] * D + d], xs[xs_base(r) + d]);
    }
}

// ---------------- finalize A: scalars (1 block) ------------------------------
__global__ void vq_final_a(const float* __restrict__ counts,
                           const float* __restrict__ loss_sum,
                           const float* __restrict__ ema_csh,  // [K]
                           const int*   __restrict__ counter,
                           float* __restrict__ out_loss,
                           float* __restrict__ out_perp,
                           float* __restrict__ out_hcs,        // [K]
                           float* __restrict__ ws_stable,      // [K]
                           float* __restrict__ ws_debias)      // [1]
{
    __shared__ float s_red[K];

    const int k = threadIdx.x;  // 512 threads
    const float c = counts[k];
    const float hid = ema_csh[k] * DECAY + c * ONE_MINUS_DECAY;
    out_hcs[k] = hid;

    const int   cnt    = counter[0] + 1;
    const float debias = 1.0f - powf(DECAY, (float)cnt);
    const float upd    = hid / debias;

    // n = sum(updated_cluster_size)
    s_red[k] = upd;
    __syncthreads();
    for (int off = 256; off >= 1; off >>= 1) {
        if (k < off) s_red[k] += s_red[k + off];
        __syncthreads();
    }
    const float n = s_red[0];
    __syncthreads();

    // entropy for perplexity
    const float p = c * (1.0f / (float)NROWS);
    s_red[k] = p * logf(p + 1e-10f);
    __syncthreads();
    for (int off = 256; off >= 1; off >>= 1) {
        if (k < off) s_red[k] += s_red[k + off];
        __syncthreads();
    }
    const float ent = s_red[0];

    ws_stable[k] = (upd + 1e-5f) / (n + (float)K * 1e-5f) * n;
    if (k == 0) {
        ws_debias[0] = debias;
        out_loss[0]  = COMMIT * loss_sum[0] / (float)((size_t)NROWS * D);
        out_perp[0]  = expf(-ent);
    }
}

// ---------------- finalize B: hdw + new embeddings (parallel) ----------------
__global__ void vq_final_b(const float* __restrict__ dw_t,      // [K][D]
                           const float* __restrict__ ema_dwh,   // [D][K]
                           const float* __restrict__ ws_stable, // [K]
                           const float* __restrict__ ws_debias,
                           float* __restrict__ out_nemb,        // [D][K]
                           float* __restrict__ out_hdw)         // [D][K]
{
    int i = blockIdx.x * 256 + threadIdx.x;  // 0..32767 (128 blocks)
    int d = i >> 9, kk = i & (K - 1);
    float hdw = ema_dwh[i] * DECAY + dw_t[kk * D + d] * ONE_MINUS_DECAY;
    out_hdw[i]  = hdw;
    out_nemb[i] = (hdw / ws_debias[0]) / ws_stable[kk];
}

// ---------------- launch ------------------------------------------------------
extern "C" void kernel_launch(void* const* d_in, const int* in_sizes, int n_in,
                              void* d_out, int out_size, void* d_ws, size_t ws_size,
                              hipStream_t stream)
{
    const float* x_in    = (const float*)d_in[0];   // [64,32,32,64]
    const float* emb     = (const float*)d_in[1];   // [64,512]
    const float* ema_csh = (const float*)d_in[2];   // [512]
    const float* ema_dwh = (const float*)d_in[3];   // [64,512]
    const int*   counter = (const int*)d_in[4];     // [1]

    float* ws  = (float*)d_ws;
    float* out = (float*)d_out;

    vq_prep<<<128, 256, 0, stream>>>(emb, ws);

    vq_main<<<NROWS / BM, 256, 0, stream>>>(
        x_in, emb, ws + WS_ESQ, ws + WS_ET,
        out + OUT_Q, out + OUT_IDX,
        ws + WS_DWT, ws + WS_COUNTS, ws + WS_LOSS);

    vq_final_a<<<1, K, 0, stream>>>(
        ws + WS_COUNTS, ws + WS_LOSS, ema_csh, counter,
        out + OUT_LOSS, out + OUT_PERP, out + OUT_HCS,
        ws + WS_STABLE, ws + WS_DEBIAS);

    vq_final_b<<<128, 256, 0, stream>>>(
        ws + WS_DWT, ema_dwh, ws + WS_STABLE, ws + WS_DEBIAS,
        out + OUT_NEMB, out + OUT_HDW);
}